// Round 1
// baseline (808.861 us; speedup 1.0000x reference)
//
#include <hip/hip_runtime.h>

// Problem: bidirectional LSTM, B=256, T=1024, V=6, D=64, U=64.
// Output = concat(h_fwd_final, h_bwd_one_step) @ Wd + bd, shape (B,1).
// Key reductions:
//  - only last timestep consumed -> forward needs full recurrence (serial),
//    backward needs exactly ONE step from h0=0 (so Wr_b is never used).
//  - vocab V=6 -> xproj has only 6 distinct values; build 6x256 table per block.

constexpr int kB = 256;
constexpr int kT = 1024;
constexpr int kV = 6;
constexpr int kD = 64;
constexpr int kU = 64;
constexpr int kG = 256; // 4*U gate columns

__device__ __forceinline__ float sigmoid_f(float z) {
    // exp(-z): overflow to +inf for very negative z -> 1/(1+inf)=0 (correct);
    // underflow to 0 for large z -> 1 (correct). No clamp needed.
    return 1.0f / (1.0f + __expf(-z));
}

__device__ __forceinline__ float tanh_f(float z) {
    z = fminf(fmaxf(z, -15.0f), 15.0f);   // e^30 ~ 1e13, no overflow
    const float e = __expf(2.0f * z);
    return (e - 1.0f) / (e + 1.0f);
}

__global__ __launch_bounds__(256) void bilstm_last_kernel(
    const int*   __restrict__ tokens, // (B,T) int32 in [0,6)
    const float* __restrict__ emb,    // (6,64)
    const float* __restrict__ Wk_f,   // (64,256) row-major
    const float* __restrict__ Wr_f,   // (64,256) row-major
    const float* __restrict__ b_f,    // (256)
    const float* __restrict__ Wk_b,   // (64,256)
    const float* __restrict__ b_b,    // (256)
    const float* __restrict__ Wd,     // (128,1) flat
    const float* __restrict__ bd,     // (1)
    float*       __restrict__ out)    // (B,1) flat
{
    __shared__ float s_emb[kV * kD];                    // 1.5 KB
    __shared__ float s_proj[kV * kG];                   // 6 KB   xproj_f table
    __shared__ int   s_tok[kT];                         // 4 KB
    __shared__ float __align__(16) s_h[kU];             // hidden state (fwd)
    __shared__ float s_act[kG];                         // 1 KB   activated gates
    __shared__ float s_hb[kU];                          // backward one-step h
    __shared__ int   s_maskv[kV];

    const int b   = blockIdx.x;
    const int tid = threadIdx.x;

    // ---- stage emb + tokens ----
    for (int i = tid; i < kV * kD; i += 256) s_emb[i] = emb[i];
    ((int4*)s_tok)[tid] = ((const int4*)(tokens + b * kT))[tid]; // 256*16B = 4KB
    if (tid < kU) s_h[tid] = 0.0f;
    __syncthreads();

    if (tid < kV) {
        int any = 0;
        for (int d = 0; d < kD; ++d) any |= (s_emb[tid * kD + d] != 0.0f) ? 1 : 0;
        s_maskv[tid] = any;
    }

    const int tokL = s_tok[kT - 1];

    // ---- per-block precompute: proj_f[v][g] for all 6 v; proj_b[tokL][g] ----
    float accf[kV];
#pragma unroll
    for (int v = 0; v < kV; ++v) accf[v] = b_f[tid];
    float accb = b_b[tid];
    for (int d = 0; d < kD; ++d) {
        const float wkf = Wk_f[d * kG + tid];
        const float wkb = Wk_b[d * kG + tid];
#pragma unroll
        for (int v = 0; v < kV; ++v)
            accf[v] = fmaf(s_emb[v * kD + d], wkf, accf[v]);
        accb = fmaf(s_emb[tokL * kD + d], wkb, accb);
    }
#pragma unroll
    for (int v = 0; v < kV; ++v) s_proj[v * kG + tid] = accf[v];

    // backward single step: z = xproj_b only (h0 = 0); c0 = 0 so f-gate dead.
    float ab;
    if (tid < 128)      ab = sigmoid_f(accb);   // i (f also, unused)
    else if (tid < 192) ab = tanh_f(accb);      // g
    else                ab = sigmoid_f(accb);   // o
    s_act[tid] = ab;
    __syncthreads();
    if (tid < kU) {
        const float cb = s_act[tid] * s_act[2 * kU + tid];   // i*g
        const float hb = s_act[3 * kU + tid] * tanh_f(cb);   // o*tanh(c)
        s_hb[tid] = s_maskv[tokL] ? hb : 0.0f;
    }

    // ---- Wr_f column into registers: w[u] = Wr_f[u][tid] ----
    float w[kU];
#pragma unroll
    for (int u = 0; u < kU; ++u) w[u] = Wr_f[u * kG + tid];

    float c = 0.0f;   // cell state, owned by threads tid < 64
    __syncthreads();  // covers s_proj, s_h init, s_maskv, s_act reuse

    // ---- forward recurrence, serial over T ----
    for (int t = 0; t < kT; ++t) {
        const int tok = s_tok[t];
        float z = s_proj[tok * kG + tid];
#pragma unroll
        for (int u = 0; u < kU; u += 4) {
            const float4 hv = *(const float4*)&s_h[u];  // broadcast read
            z = fmaf(hv.x, w[u + 0], z);
            z = fmaf(hv.y, w[u + 1], z);
            z = fmaf(hv.z, w[u + 2], z);
            z = fmaf(hv.w, w[u + 3], z);
        }
        float a;
        if (tid < 128)      a = sigmoid_f(z);  // i, f  (waves 0,1)
        else if (tid < 192) a = tanh_f(z);     // g     (wave 2)
        else                a = sigmoid_f(z);  // o     (wave 3)
        s_act[tid] = a;
        __syncthreads();
        if (tid < kU) {
            const float i_ = s_act[tid];
            const float f_ = s_act[kU + tid];
            const float g_ = s_act[2 * kU + tid];
            const float o_ = s_act[3 * kU + tid];
            const float cn = fmaf(f_, c, i_ * g_);
            const float hn = o_ * tanh_f(cn);
            if (s_maskv[tok]) {
                c = cn;
                s_h[tid] = hn;
            }
        }
        __syncthreads();
    }

    // ---- epilogue: out[b] = h_f . Wd[0:64] + h_b . Wd[64:128] + bd ----
    if (tid < kU) {
        float v = s_h[tid] * Wd[tid] + s_hb[tid] * Wd[kU + tid];
#pragma unroll
        for (int off = 32; off > 0; off >>= 1) v += __shfl_down(v, off, 64);
        if (tid == 0) out[b] = v + bd[0];
    }
}

extern "C" void kernel_launch(void* const* d_in, const int* in_sizes, int n_in,
                              void* d_out, int out_size, void* d_ws, size_t ws_size,
                              hipStream_t stream) {
    const int*   tokens = (const int*)d_in[0];
    const float* emb    = (const float*)d_in[1];
    const float* Wk_f   = (const float*)d_in[2];
    const float* Wr_f   = (const float*)d_in[3];
    const float* b_f    = (const float*)d_in[4];
    const float* Wk_b   = (const float*)d_in[5];
    // d_in[6] = Wr_b: provably unused (backward direction runs exactly one
    // step from h0=0, so the recurrent term is zero).
    const float* b_b    = (const float*)d_in[7];
    const float* Wd     = (const float*)d_in[8];
    const float* bd     = (const float*)d_in[9];
    float* out = (float*)d_out;

    bilstm_last_kernel<<<kB, 256, 0, stream>>>(
        tokens, emb, Wk_f, Wr_f, b_f, Wk_b, b_b, Wd, bd, out);
}

// Round 2
// 689.967 us; speedup vs baseline: 1.1723x; 1.1723x over previous
//
#include <hip/hip_runtime.h>

// Bidirectional LSTM, B=256, T=1024, V=6, D=64, U=64; output = last-step
// concat(h_f, h_b) @ Wd + bd, shape (B,1).
// Reductions: backward dir needs exactly ONE step from h0=0 (Wr_b dead);
// V=6 -> xproj is a 6x256 table per block.
// R2 structure: gate-interleaved lanes + shfl gather + double-buffered h
// -> ONE barrier per step; token/proj path software-pipelined.

constexpr int kB = 256;
constexpr int kT = 1024;
constexpr int kV = 6;
constexpr int kD = 64;
constexpr int kU = 64;
constexpr int kG = 256; // 4*U gate columns

__device__ __forceinline__ float sigmoid_f(float z) {
    return 1.0f / (1.0f + __expf(-z));   // saturates correctly at +-inf
}
__device__ __forceinline__ float tanh_fast(float x) {
    // 2*sigma(2x)-1; exp overflow/underflow saturate to +-1 correctly
    return 2.0f / (1.0f + __expf(-2.0f * x)) - 1.0f;
}

__global__ __launch_bounds__(256) void bilstm_last_kernel(
    const int*   __restrict__ tokens, // (B,T)
    const float* __restrict__ emb,    // (6,64)
    const float* __restrict__ Wk_f,   // (64,256)
    const float* __restrict__ Wr_f,   // (64,256)
    const float* __restrict__ b_f,    // (256)
    const float* __restrict__ Wk_b,   // (64,256)
    const float* __restrict__ b_b,    // (256)
    const float* __restrict__ Wd,     // (128)
    const float* __restrict__ bd,     // (1)
    float*       __restrict__ out)    // (B)
{
    __shared__ float s_emb[kV * kD];
    __shared__ float s_projP[kV * kG];            // PERMUTED xproj_f table
    __shared__ int   s_tok[kT];
    __shared__ float __align__(16) s_h[2][kU];    // double-buffered hidden
    __shared__ float s_act[kG];                   // backward-step scratch
    __shared__ float s_hb[kU];
    __shared__ int   s_maskv[kV];

    const int b   = blockIdx.x;
    const int tid = threadIdx.x;
    const int l   = tid & 63;       // lane in wave
    const int wv  = tid >> 6;       // wave id 0..3
    const int g   = l & 3;          // gate 0..3 (i,f,g,o)
    const int k   = l >> 2;         // 0..15
    const int u   = wv * 16 + k;    // unit 0..63 owned by this lane group
    const int col = g * 64 + u;     // gate column this lane computes

    // ---- stage emb + tokens ----
    for (int i = tid; i < kV * kD; i += 256) s_emb[i] = emb[i];
    ((int4*)s_tok)[tid] = ((const int4*)(tokens + b * kT))[tid];
    if (tid < kU) { s_h[0][tid] = 0.0f; s_h[1][tid] = 0.0f; }
    __syncthreads();

    if (tid < kV) {
        int any = 0;
        for (int d = 0; d < kD; ++d) any |= (s_emb[tid * kD + d] != 0.0f) ? 1 : 0;
        s_maskv[tid] = any;
    }

    const int tokL = s_tok[kT - 1];

    // ---- proj table: column 'tid' (coalesced global reads), then permuted
    // store so the step loop reads s_projP[v*256 + tid] = proj[v][col(tid)].
    float accf[kV];
#pragma unroll
    for (int v = 0; v < kV; ++v) accf[v] = b_f[tid];
    float accb = b_b[tid];
    for (int d = 0; d < kD; ++d) {
        const float wkf = Wk_f[d * kG + tid];
        const float wkb = Wk_b[d * kG + tid];
#pragma unroll
        for (int v = 0; v < kV; ++v)
            accf[v] = fmaf(s_emb[v * kD + d], wkf, accf[v]);
        accb = fmaf(s_emb[tokL * kD + d], wkb, accb);
    }
    {   // inverse permutation: lane q with col(q)==tid is q = w0*64 + k0*4 + g0
        const int g0 = tid >> 6, u0 = tid & 63, w0 = u0 >> 4, k0 = u0 & 15;
        const int q = w0 * 64 + k0 * 4 + g0;
#pragma unroll
        for (int v = 0; v < kV; ++v) s_projP[v * kG + q] = accf[v];
    }

    // ---- backward single step: z = xproj_b only (h0=0, c0=0 -> f dead) ----
    float ab;
    if (tid < 128)      ab = sigmoid_f(accb);
    else if (tid < 192) ab = tanh_fast(accb);
    else                ab = sigmoid_f(accb);
    s_act[tid] = ab;
    __syncthreads();   // also makes s_maskv visible
    if (tid < kU) {
        const float cb = s_act[tid] * s_act[2 * kU + tid];
        const float hb = s_act[3 * kU + tid] * tanh_fast(cb);
        s_hb[tid] = s_maskv[tokL] ? hb : 0.0f;
    }

    // ---- recurrent weights for this lane's gate column ----
    float wr[kU];
#pragma unroll
    for (int j = 0; j < kU; ++j) wr[j] = Wr_f[j * kG + col];

    float c = 0.0f, hreg = 0.0f;
    __syncthreads();   // projP + s_h init + s_hb visible

    // ---- software-pipelined token path ----
    int   tok  = s_tok[0];
    float zcur = s_projP[tok * kG + tid];
    int   msk  = s_maskv[tok];

    const int base = l & ~3;

    for (int t = 0; t < kT; ++t) {
        const int rp = t & 1, wp = rp ^ 1;

        // prefetch next step's token/proj/mask (projP is constant -> legal)
        const int   tokn  = s_tok[(t + 1) & (kT - 1)];
        const float znext = s_projP[tokn * kG + tid];
        const int   mskn  = s_maskv[tokn];

        // h broadcast loads (16 x b128, same-address broadcast: conflict-free)
        float4 h4[16];
#pragma unroll
        for (int j = 0; j < 16; ++j) h4[j] = ((const float4*)s_h[rp])[j];

        // 64 MACs, 4 independent chains
        float z0 = zcur, z1 = 0.0f, z2 = 0.0f, z3 = 0.0f;
#pragma unroll
        for (int j = 0; j < 16; ++j) {
            z0 = fmaf(h4[j].x, wr[4 * j + 0], z0);
            z1 = fmaf(h4[j].y, wr[4 * j + 1], z1);
            z2 = fmaf(h4[j].z, wr[4 * j + 2], z2);
            z3 = fmaf(h4[j].w, wr[4 * j + 3], z3);
        }
        const float z = (z0 + z1) + (z2 + z3);

        // one exp: gate 2 uses tanh(z) = 2*sigmoid(2z)-1
        const bool  isg = (g == 2);
        const float zz  = isg ? 2.0f * z : z;
        const float s   = 1.0f / (1.0f + __expf(-zz));
        const float a   = isg ? 2.0f * s - 1.0f : s;

        // gather i,f,g,o from the 4 lanes of this unit's quad
        const float ai = __shfl(a, base + 0, 64);
        const float af = __shfl(a, base + 1, 64);
        const float ag = __shfl(a, base + 2, 64);
        const float ao = __shfl(a, base + 3, 64);

        const float cn = fmaf(af, c, ai * ag);
        const float hn = ao * tanh_fast(cn);
        if (msk) { c = cn; hreg = hn; }

        if (g == 0) s_h[wp][u] = hreg;
        __syncthreads();

        zcur = znext; msk = mskn; tok = tokn;
    }

    // final h is in s_h[0] (step 1023 writes buffer (1024)&1 == 0)
    if (tid < kU) {
        float v = s_h[0][tid] * Wd[tid] + s_hb[tid] * Wd[kU + tid];
#pragma unroll
        for (int off = 32; off > 0; off >>= 1) v += __shfl_down(v, off, 64);
        if (tid == 0) out[b] = v + bd[0];
    }
}

extern "C" void kernel_launch(void* const* d_in, const int* in_sizes, int n_in,
                              void* d_out, int out_size, void* d_ws, size_t ws_size,
                              hipStream_t stream) {
    const int*   tokens = (const int*)d_in[0];
    const float* emb    = (const float*)d_in[1];
    const float* Wk_f   = (const float*)d_in[2];
    const float* Wr_f   = (const float*)d_in[3];
    const float* b_f    = (const float*)d_in[4];
    const float* Wk_b   = (const float*)d_in[5];
    // d_in[6] = Wr_b: unused (backward runs one step from h0=0)
    const float* b_b    = (const float*)d_in[7];
    const float* Wd     = (const float*)d_in[8];
    const float* bd     = (const float*)d_in[9];
    float* out = (float*)d_out;

    bilstm_last_kernel<<<kB, 256, 0, stream>>>(
        tokens, emb, Wk_f, Wr_f, b_f, Wk_b, b_b, Wd, bd, out);
}